// Round 9
// baseline (509.008 us; speedup 1.0000x reference)
//
#include <hip/hip_runtime.h>
#include <math.h>

typedef __bf16 bf16_t;
typedef bf16_t bf16x8 __attribute__((ext_vector_type(8)));
typedef float  floatx4 __attribute__((ext_vector_type(4)));

#define MFMA16(a, b, c) __builtin_amdgcn_mfma_f32_16x16x32_bf16((a), (b), (c), 0, 0, 0)

// Problem constants
constexpr int NTOT = 256 * 512;   // 131072 samples
constexpr int CDIM = 256;         // K for all GEMMs

// ws: flat stream of 88 weight tiles in USE ORDER; tile = 16 output cols x 256 k
// in MFMA B-fragment order: tile[ks][lane][j] (8 KB). Wave B-load = contiguous 1 KB.
// ORDER (B1 first):
//   tiles  0..3  : wb1   (phase B1, groups  0..1)
//   tiles  4..19 : w1a   (phase A,  groups  2..9)
//   tiles 20..51 : w1b   (phase B2, groups 10..25)
//   tiles 52..67 : w2a   (phase C,  groups 26..33)
//   tiles 68..71 : w2b   (phase D,  groups 34..35)
//   tiles 72..87 : wb2a  (phase E,  groups 36..43)
constexpr int N_TILES  = 88;
constexpr int WS_ELEMS = N_TILES * 4096;

// ---------------------------------------------------------------------------
__global__ void prep_weights(const float* __restrict__ w1a, const float* __restrict__ w1b,
                             const float* __restrict__ w2a, const float* __restrict__ w2b,
                             const float* __restrict__ wb1, const float* __restrict__ wb2a,
                             bf16_t* __restrict__ ws) {
  int idx = blockIdx.x * 256 + threadIdx.x;
  if (idx >= WS_ELEMS) return;
  int t   = idx >> 12;       // tile
  int rel = idx & 4095;
  const float* src; int dout; int ct;
  if      (t < 4)  { src = wb1;  dout = 64;  ct = t; }
  else if (t < 20) { src = w1a;  dout = 256; ct = t - 4; }
  else if (t < 52) { src = w1b;  dout = 512; ct = t - 20; }
  else if (t < 68) { src = w2a;  dout = 256; ct = t - 52; }
  else if (t < 72) { src = w2b;  dout = 64;  ct = t - 68; }
  else             { src = wb2a; dout = 256; ct = t - 72; }
  int j    = rel & 7;
  int lane = (rel >> 3) & 63;
  int ks   = rel >> 9;
  int o = ct * 16 + (lane & 15);
  int k = ks * 32 + (lane >> 4) * 8 + j;
  ws[idx] = (bf16_t)src[(size_t)k * dout + o];
}

// async global->LDS, 16 B per lane; LDS dest = wave-uniform base + lane*16
__device__ __forceinline__ void gload_lds16(const bf16_t* g, bf16_t* l) {
  __builtin_amdgcn_global_load_lds(
      (const __attribute__((address_space(1))) unsigned int*)g,
      (__attribute__((address_space(3))) unsigned int*)l, 16, 0, 0);
}

// ---------------------------------------------------------------------------
// rt=2 (32 rows/wave) AT 3 WAVES/SIMD, TRANSIENT-CAPPED REMAT (R8 post-mortem).
//
// Model (R0/R6/R7/R8-constrained): per-wave B-feed bytes = 16KB/group,
// invariant across pipes (R8 disproved split-pipe); only rows/wave cuts it.
// R6 (16 rows, 4 w/SIMD) is LDS-pipe-bound (~82% busy = 137us of 167).
// R0 (32 rows, 2 w/SIMD) is latency-bound (LDS only 31%). Target quadrant:
// 32 rows at 3 w/SIMD needs <=170 regs. R7 failed there because loadSA held
// 16 float4 = 64 TRANSIENT regs atop ~150 persistent (demand ~210 -> total
// scratch dump, 250 MB WRITE). Fixes here:
//   1. remat throttled: one fragment at a time, sched_barrier(0) after each
//      -> transients ~8 regs, indices still compile-time (no demotion).
//   2. hid parked as packed bf16 (hidp, 16 regs) through phases A and C;
//      unpacked f32 only in B2/D where accumulated.
//   3. phase order B1->A->B2->C->D->E so sA is dead during B2 and D.
// Budget: peak ~= sA64+hA64+hidp16+~18 = ~162 vs cap 170 (margin +8; R7 was
// -40). LDS 46,080 x 3 = 138 KB <= 160. Grid 1024 at 3 blocks/CU (768
// resident; ~8% tail cost accepted).
//
// Tripwire: WRITE_SIZE > 20 MB = spill => R6 is final; next try R6+setprio.
// Expected FETCH ~300-340 MB (st remat from L3) -- priced in, NOT a failure.
//
// CRITICAL: every register array (sA, hA, hid, hidp, p) indexed ONLY with
// compile-time constants, else LLVM demotes to scratch. Full unrolling below.
// ---------------------------------------------------------------------------
__global__ __launch_bounds__(256, 3)
void mixing_fused(const float* __restrict__ q,     // [N,8]
                  const float* __restrict__ st,    // [N,256]
                  const bf16_t* __restrict__ W,    // ws (tile stream)
                  const float* __restrict__ b1a, const float* __restrict__ b1b,
                  const float* __restrict__ b2a, const float* __restrict__ b2b,
                  const float* __restrict__ bb1,
                  const float* __restrict__ bb2a,
                  const float* __restrict__ wb2b, const float* __restrict__ bb2b,
                  float* __restrict__ out) {
  __shared__ __align__(16) bf16_t wbuf[2][8192];  // 2 x 16 KB weight groups
  __shared__ __align__(16) bf16_t t_s[4][32][36]; // per-wave bounce (transpose)
  __shared__ __align__(16) float  q_s[4][256];    // per-wave q staging

  const int tid  = threadIdx.x;
  const int wid  = tid >> 6;      // 0..3
  const int lane = tid & 63;
  const int l15  = lane & 15;
  const int quad = lane >> 4;
  const int m0   = blockIdx.x * 128 + wid * 32;

  // wave-cooperative stage of group g (16 KB) into wbuf[g&1]; 4 KB per wave
  auto stage = [&](int g) {
    const bf16_t* src = W + (size_t)g * 8192 + wid * 2048 + lane * 8;
    bf16_t* dst = &wbuf[g & 1][wid * 2048];
#pragma unroll
    for (int i = 0; i < 4; ++i)
      gload_lds16(src + i * 512, dst + i * 512);
  };

  // ---- wave-local q staging ----
  *(float4*)&q_s[wid][lane * 4] = *(const float4*)(q + (size_t)m0 * 8 + lane * 4);

  // st A-fragment (re)load, TRANSIENT-CAPPED: one frag at a time, fenced with
  // sched_barrier(0) so the scheduler cannot batch 16 float4 loads (R7's
  // 64-reg transient spike). Indices fully static.
  auto loadSA = [&](bf16x8 (&A)[2][8]) {
#pragma unroll
    for (int rt = 0; rt < 2; ++rt) {
      const float* rp = st + (size_t)(m0 + rt * 16 + l15) * CDIM;
#pragma unroll
      for (int ks = 0; ks < 8; ++ks) {
        int k0 = ks * 32 + quad * 8;
        float4 f0 = *(const float4*)(rp + k0);
        float4 f1 = *(const float4*)(rp + k0 + 4);
        bf16x8 v;
        v[0] = (bf16_t)f0.x; v[1] = (bf16_t)f0.y; v[2] = (bf16_t)f0.z; v[3] = (bf16_t)f0.w;
        v[4] = (bf16_t)f1.x; v[5] = (bf16_t)f1.y; v[6] = (bf16_t)f1.z; v[7] = (bf16_t)f1.w;
        A[rt][ks] = v;
        __builtin_amdgcn_sched_barrier(0);
      }
    }
  };

  // GEMM: 16-col tile h (0/1) of LDS group buffer `buf`, both row tiles.
  // One B-frag read feeds TWO MFMAs (the point of rt=2).
  auto gemmL = [&](int buf, int h, const bf16x8 (&A)[2][8], floatx4 (&acc)[2]) {
    floatx4 z = {0.f, 0.f, 0.f, 0.f};
    acc[0] = z; acc[1] = z;
#pragma unroll
    for (int kk = 0; kk < 8; ++kk) {
      bf16x8 b = *(const bf16x8*)&wbuf[buf][h * 4096 + kk * 512 + lane * 8];
      acc[0] = MFMA16(A[0][kk], b, acc[0]);
      acc[1] = MFMA16(A[1][kk], b, acc[1]);
    }
  };

  bf16x8 sA[2][8];
  loadSA(sA);

  stage(0);

  // ========= Phase B1 (FIRST): hid = st @ wb1 + bb1   groups 0..1 ===========
  floatx4 hid[2][4];
#pragma unroll
  for (int gg = 0; gg < 2; ++gg) {
    __syncthreads();
    stage(1 + gg);
    const int buf = gg & 1;
#pragma unroll
    for (int h = 0; h < 2; ++h) {
      int et = 2 * gg + h;
      floatx4 acc[2];
      gemmL(buf, h, sA, acc);
      float bias = bb1[et * 16 + l15];
      hid[0][et] = acc[0] + bias;
      hid[1][et] = acc[1] + bias;
    }
  }
  // pack hid -> bf16 (16 regs) so it stays cheap through phase A
  bf16x8 hidp[2][2];
#pragma unroll
  for (int rt = 0; rt < 2; ++rt)
#pragma unroll
    for (int g = 0; g < 2; ++g)
#pragma unroll
      for (int j = 0; j < 8; ++j)
        hidp[rt][g][j] = (bf16_t)hid[rt][g * 2 + (j >> 2)][j & 3];

  // ========= Phase A: H1 = elu(st @ w1a + b1a)   groups 2..9 ================
  bf16x8 hA[2][8];
#pragma unroll
  for (int ks = 0; ks < 8; ++ks) {
    __syncthreads();
    stage(3 + ks);
    const int buf = ks & 1;
#pragma unroll
    for (int h = 0; h < 2; ++h) {
      int ct = 2 * ks + h;
      floatx4 acc[2];
      gemmL(buf, h, sA, acc);
      float bias = b1a[ct * 16 + l15];
#pragma unroll
      for (int rt = 0; rt < 2; ++rt)
#pragma unroll
        for (int i = 0; i < 4; ++i) {
          float v = acc[rt][i] + bias;
          v = v > 0.f ? v : (__expf(v) - 1.f);
          t_s[wid][rt * 16 + quad * 4 + i][h * 16 + l15] = (bf16_t)v;
        }
    }
#pragma unroll
    for (int rt = 0; rt < 2; ++rt)
      hA[rt][ks] = *(const bf16x8*)&t_s[wid][rt * 16 + l15][quad * 8];
  }
  // sA DEAD from here until the loadSA before phase C (B2 uses hA only).

  // ==== Phase B2: W1 = |H1 @ w1b + b1b|; hid += q.*W1   groups 10..25 ========
  // unpack hid to f32 for accumulation
#pragma unroll
  for (int rt = 0; rt < 2; ++rt)
#pragma unroll
    for (int g = 0; g < 2; ++g)
#pragma unroll
      for (int j = 0; j < 8; ++j)
        hid[rt][g * 2 + (j >> 2)][j & 3] = (float)hidp[rt][g][j];

#pragma unroll 1
  for (int a = 0; a < 8; ++a) {
    float qv[2][4];
#pragma unroll
    for (int rt = 0; rt < 2; ++rt)
#pragma unroll
      for (int i = 0; i < 4; ++i)
        qv[rt][i] = q_s[wid][(rt * 16 + quad * 4 + i) * 8 + a];
#pragma unroll
    for (int g2 = 0; g2 < 2; ++g2) {
      const int idx = a * 2 + g2;          // 0..15
      __syncthreads();
      stage(11 + idx);
      const int buf = g2;                  // (10+idx)&1 == g2
#pragma unroll
      for (int h = 0; h < 2; ++h) {
        int ct = a * 4 + g2 * 2 + h;
        const int et = g2 * 2 + h;         // constant
        floatx4 acc[2];
        gemmL(buf, h, hA, acc);
        float bias = b1b[ct * 16 + l15];
#pragma unroll
        for (int rt = 0; rt < 2; ++rt)
#pragma unroll
          for (int i = 0; i < 4; ++i) {
            float w1v = fabsf(acc[rt][i] + bias);
            hid[rt][et][i] += qv[rt][i] * w1v;
          }
      }
    }
  }
  // relu + repack (hid parked as bf16 through phase C)
#pragma unroll
  for (int rt = 0; rt < 2; ++rt)
#pragma unroll
    for (int g = 0; g < 2; ++g)
#pragma unroll
      for (int j = 0; j < 8; ++j)
        hidp[rt][g][j] = (bf16_t)fmaxf(hid[rt][g * 2 + (j >> 2)][j & 3], 0.f);

  // ========= Phase C: H2 = elu(st @ w2a + b2a)  groups 26..33 ===============
  loadSA(sA);                              // transient-capped remat (L3 st)
#pragma unroll
  for (int ks = 0; ks < 8; ++ks) {
    __syncthreads();
    stage(27 + ks);
    const int buf = ks & 1;
#pragma unroll
    for (int h = 0; h < 2; ++h) {
      int ct = 2 * ks + h;
      floatx4 acc[2];
      gemmL(buf, h, sA, acc);
      float bias = b2a[ct * 16 + l15];
#pragma unroll
      for (int rt = 0; rt < 2; ++rt)
#pragma unroll
        for (int i = 0; i < 4; ++i) {
          float v = acc[rt][i] + bias;
          v = v > 0.f ? v : (__expf(v) - 1.f);
          t_s[wid][rt * 16 + quad * 4 + i][h * 16 + l15] = (bf16_t)v;
        }
    }
#pragma unroll
    for (int rt = 0; rt < 2; ++rt)
      hA[rt][ks] = *(const bf16x8*)&t_s[wid][rt * 16 + l15][quad * 8];
  }
  // sA dead again until the loadSA before phase E.

  // ==== Phase D: W2 = |H2 @ w2b + b2b|; p += hid*W2   groups 34..35 =========
#pragma unroll
  for (int rt = 0; rt < 2; ++rt)
#pragma unroll
    for (int g = 0; g < 2; ++g)
#pragma unroll
      for (int j = 0; j < 8; ++j)
        hid[rt][g * 2 + (j >> 2)][j & 3] = (float)hidp[rt][g][j];

  float p[2][4] = {{0.f, 0.f, 0.f, 0.f}, {0.f, 0.f, 0.f, 0.f}};
#pragma unroll
  for (int gg = 0; gg < 2; ++gg) {
    __syncthreads();
    stage(35 + gg);
    const int buf = gg & 1;
#pragma unroll
    for (int h = 0; h < 2; ++h) {
      int et = 2 * gg + h;
      floatx4 acc[2];
      gemmL(buf, h, hA, acc);
      float bias = b2b[et * 16 + l15];
#pragma unroll
      for (int rt = 0; rt < 2; ++rt)
#pragma unroll
        for (int i = 0; i < 4; ++i) {
          float w2v = fabsf(acc[rt][i] + bias);
          p[rt][i] += hid[rt][et][i] * w2v;
        }
    }
  }

  // == Phase E: HB = elu(st @ wb2a + bb2a); p += HB*wb2b   groups 36..43 =====
  loadSA(sA);                              // transient-capped remat #2
#pragma unroll 1
  for (int gg = 0; gg < 8; ++gg) {
    __syncthreads();
    if (gg < 7) stage(37 + gg);
    const int buf = gg & 1;
#pragma unroll
    for (int h = 0; h < 2; ++h) {
      int ct = 2 * gg + h;
      floatx4 acc[2];
      gemmL(buf, h, sA, acc);
      float bias = bb2a[ct * 16 + l15];
      float wv   = wb2b[ct * 16 + l15];
#pragma unroll
      for (int rt = 0; rt < 2; ++rt)
#pragma unroll
        for (int i = 0; i < 4; ++i) {
          float v = acc[rt][i] + bias;
          v = v > 0.f ? v : (__expf(v) - 1.f);
          p[rt][i] += v * wv;
        }
    }
  }

  // ======= Reduce over 16 column lanes (same row), store joint output ========
  float bb2 = bb2b[0];
#pragma unroll
  for (int rt = 0; rt < 2; ++rt)
#pragma unroll
    for (int i = 0; i < 4; ++i) {
      float v = p[rt][i];
      v += __shfl_xor(v, 1);
      v += __shfl_xor(v, 2);
      v += __shfl_xor(v, 4);
      v += __shfl_xor(v, 8);
      if (l15 == 0) out[m0 + rt * 16 + quad * 4 + i] = v + bb2;
    }
}

// ---------------------------------------------------------------------------
extern "C" void kernel_launch(void* const* d_in, const int* in_sizes, int n_in,
                              void* d_out, int out_size, void* d_ws, size_t ws_size,
                              hipStream_t stream) {
  const float* q    = (const float*)d_in[0];
  const float* st   = (const float*)d_in[1];
  const float* w1a  = (const float*)d_in[2];
  const float* b1a  = (const float*)d_in[3];
  const float* w1b  = (const float*)d_in[4];
  const float* b1b  = (const float*)d_in[5];
  const float* w2a  = (const float*)d_in[6];
  const float* b2a  = (const float*)d_in[7];
  const float* w2b  = (const float*)d_in[8];
  const float* b2b  = (const float*)d_in[9];
  const float* wb1  = (const float*)d_in[10];
  const float* bb1  = (const float*)d_in[11];
  const float* wb2a = (const float*)d_in[12];
  const float* bb2a = (const float*)d_in[13];
  const float* wb2b = (const float*)d_in[14];
  const float* bb2b = (const float*)d_in[15];
  bf16_t* W = (bf16_t*)d_ws;

  hipLaunchKernelGGL(prep_weights, dim3((WS_ELEMS + 255) / 256), dim3(256), 0, stream,
                     w1a, w1b, w2a, w2b, wb1, wb2a, W);
  hipLaunchKernelGGL(mixing_fused, dim3(NTOT / 128), dim3(256), 0, stream,
                     q, st, W, b1a, b1b, b2a, b2b, bb1, bb2a, wb2b, bb2b, (float*)d_out);
}